// Round 1
// baseline (562.152 us; speedup 1.0000x reference)
//
#include <hip/hip_runtime.h>
#include <cstdint>
#include <cstddef>

typedef __attribute__((ext_vector_type(8))) short short8;
typedef __attribute__((ext_vector_type(4))) float f32x4;
typedef __attribute__((ext_vector_type(4))) short short4v;

__device__ __forceinline__ unsigned short f2bf(float f) {
  unsigned u = __builtin_bit_cast(unsigned, f);
  u += 0x7fffu + ((u >> 16) & 1u);   // round-to-nearest-even
  return (unsigned short)(u >> 16);
}

// ---------------- kernel 0: fp32 -> bf16 weight conversion ----------------
__global__ __launch_bounds__(256) void cvt_k(const float* __restrict__ src,
                                             unsigned short* __restrict__ dst, int n) {
  int i = (blockIdx.x * 256 + threadIdx.x) * 4;
  if (i + 3 < n) {
    float4 v = *(const float4*)(src + i);
    short4v o;
    o.x = (short)f2bf(v.x); o.y = (short)f2bf(v.y);
    o.z = (short)f2bf(v.z); o.w = (short)f2bf(v.w);
    *(short4v*)(dst + i) = o;
  }
}

// ---------------- kernel 1: stage-1 GEMM + block-transpose write ----------
// Per k-block (kb=0..3): C1[b, q] = sum_p x[b, kb*1024+p] * w1[kb, q, p]
// Written transposed: Y[b*768 + (q/48)*192 + kb*48 + (q%48)]  (bf16)
// Tile: 128 rows x 192 cols (full N), BK=64, 256 threads (4 waves, 2x2 grid).
#define S1_LDA 72   // 64 + 8 pad: 144 B row stride (16B-aligned, bank-rotating)
__global__ __launch_bounds__(256) void stage1_k(
    const float* __restrict__ x, const unsigned short* __restrict__ w1bf,
    unsigned short* __restrict__ Y) {
  __shared__ __attribute__((aligned(16))) unsigned short As[128 * S1_LDA];
  __shared__ __attribute__((aligned(16))) unsigned short Bs[192 * S1_LDA];
  const int t  = threadIdx.x;
  const int r0 = blockIdx.x * 128;
  const int kb = blockIdx.y;

  const int lane = t & 63;
  const int w  = t >> 6;
  const int wm = w & 1, wn = w >> 1;
  const int lm = lane & 15;   // m (A) / n (B) / col (C)
  const int lk = lane >> 4;   // k-group 0..3

  // A staging: thread -> (row, 32-col half) of the 128x64 fp32 tile
  const int ar = t >> 1;
  const int ac = (t & 1) * 32;
  const float* xp = x + (size_t)(r0 + ar) * 4096 + kb * 1024 + ac;
  unsigned short* asp = &As[ar * S1_LDA + ac];

  f32x4 acc[4][6];
#pragma unroll
  for (int i = 0; i < 4; ++i)
#pragma unroll
    for (int j = 0; j < 6; ++j) acc[i][j] = (f32x4)0.0f;

  for (int kt = 0; kt < 16; ++kt) {
    // ---- stage A: load 32 fp32, convert, write 4x16B to LDS ----
    float4 v[8];
    const float* xq = xp + kt * 64;
#pragma unroll
    for (int i = 0; i < 8; ++i) v[i] = *(const float4*)(xq + i * 4);
#pragma unroll
    for (int i = 0; i < 4; ++i) {
      float4 a0 = v[2 * i], a1 = v[2 * i + 1];
      short8 o;
      o[0] = (short)f2bf(a0.x); o[1] = (short)f2bf(a0.y);
      o[2] = (short)f2bf(a0.z); o[3] = (short)f2bf(a0.w);
      o[4] = (short)f2bf(a1.x); o[5] = (short)f2bf(a1.y);
      o[6] = (short)f2bf(a1.z); o[7] = (short)f2bf(a1.w);
      *(short8*)(asp + i * 8) = o;
    }
    // ---- stage B: 192x64 bf16 tile of w1bf (already bf16) ----
#pragma unroll
    for (int i = 0; i < 6; ++i) {
      int c = t + 256 * i;          // 0..1535 chunk id (16 B each)
      int br = c >> 3, bs = c & 7;
      const uint4* gsrc = (const uint4*)(w1bf + (size_t)(kb * 192 + br) * 1024 + kt * 64 + bs * 8);
      *(uint4*)&Bs[br * S1_LDA + bs * 8] = *gsrc;
    }
    __syncthreads();
    // ---- MFMA: 2 k-steps of 32 ----
#pragma unroll
    for (int ks = 0; ks < 2; ++ks) {
      const int ko = ks * 32 + lk * 8;
      short8 a[4], b[6];
#pragma unroll
      for (int rt = 0; rt < 4; ++rt)
        a[rt] = *(const short8*)&As[(wm * 64 + rt * 16 + lm) * S1_LDA + ko];
#pragma unroll
      for (int ct = 0; ct < 6; ++ct)
        b[ct] = *(const short8*)&Bs[(wn * 96 + ct * 16 + lm) * S1_LDA + ko];
#pragma unroll
      for (int rt = 0; rt < 4; ++rt)
#pragma unroll
        for (int ct = 0; ct < 6; ++ct)
          acc[rt][ct] = __builtin_amdgcn_mfma_f32_16x16x32_bf16(a[rt], b[ct], acc[rt][ct], 0, 0, 0);
    }
    __syncthreads();
  }

  // ---- epilogue: transposed bf16 write to Y ----
#pragma unroll
  for (int rt = 0; rt < 4; ++rt) {
#pragma unroll
    for (int ct = 0; ct < 6; ++ct) {
      int q  = wn * 96 + ct * 16 + lm;          // 0..191
      int li = q / 48, j = q - li * 48;
      size_t base = (size_t)(r0 + wm * 64 + rt * 16 + lk * 4) * 768 + li * 192 + kb * 48 + j;
#pragma unroll
      for (int reg = 0; reg < 4; ++reg)
        Y[base + (size_t)reg * 768] = f2bf(acc[rt][ct][reg]);
    }
  }
}

// ---------------- kernel 2: stage-2 GEMM + bias ---------------------------
// Per l (0..3): out[b, l*1024+s] = sum_r Y[b, l, r] * w2[l, s, r] + bias
// Tile: 128 rows x 128 cols, BK=96 (2 iters), 256 threads (2x2 wave grid).
#define S2_LDA 104  // 96 + 8 pad: 208 B row stride
__global__ __launch_bounds__(256) void stage2_k(
    const unsigned short* __restrict__ Y, const unsigned short* __restrict__ w2bf,
    const float* __restrict__ bias, float* __restrict__ out) {
  __shared__ __attribute__((aligned(16))) unsigned short As[128 * S2_LDA];
  __shared__ __attribute__((aligned(16))) unsigned short Bs[128 * S2_LDA];
  const int t  = threadIdx.x;
  const int n0 = blockIdx.x * 128;
  const int r0 = blockIdx.y * 128;
  const int l  = blockIdx.z;

  const int lane = t & 63;
  const int w  = t >> 6;
  const int wm = w & 1, wn = w >> 1;
  const int lm = lane & 15;
  const int lk = lane >> 4;

  f32x4 acc[4][4];
#pragma unroll
  for (int i = 0; i < 4; ++i)
#pragma unroll
    for (int j = 0; j < 4; ++j) acc[i][j] = (f32x4)0.0f;

  for (int kt = 0; kt < 2; ++kt) {
    // stage A (Y tile 128x96 bf16) and B (w2 tile 128x96 bf16)
#pragma unroll
    for (int i = 0; i < 6; ++i) {
      int c = t + 256 * i;          // 0..1535; 12 chunks/row
      int row = c / 12, s = c - row * 12;
      const uint4* ga = (const uint4*)(Y + (size_t)(r0 + row) * 768 + l * 192 + kt * 96 + s * 8);
      *(uint4*)&As[row * S2_LDA + s * 8] = *ga;
      const uint4* gb = (const uint4*)(w2bf + (size_t)(l * 1024 + n0 + row) * 192 + kt * 96 + s * 8);
      *(uint4*)&Bs[row * S2_LDA + s * 8] = *gb;
    }
    __syncthreads();
#pragma unroll
    for (int ks = 0; ks < 3; ++ks) {
      const int ko = ks * 32 + lk * 8;
      short8 a[4], b[4];
#pragma unroll
      for (int rt = 0; rt < 4; ++rt)
        a[rt] = *(const short8*)&As[(wm * 64 + rt * 16 + lm) * S2_LDA + ko];
#pragma unroll
      for (int ct = 0; ct < 4; ++ct)
        b[ct] = *(const short8*)&Bs[(wn * 64 + ct * 16 + lm) * S2_LDA + ko];
#pragma unroll
      for (int rt = 0; rt < 4; ++rt)
#pragma unroll
        for (int ct = 0; ct < 4; ++ct)
          acc[rt][ct] = __builtin_amdgcn_mfma_f32_16x16x32_bf16(a[rt], b[ct], acc[rt][ct], 0, 0, 0);
    }
    __syncthreads();
  }

  // epilogue: fp32 out + bias
  float bv[4];
#pragma unroll
  for (int ct = 0; ct < 4; ++ct)
    bv[ct] = bias[l * 1024 + n0 + wn * 64 + ct * 16 + lm];
#pragma unroll
  for (int rt = 0; rt < 4; ++rt) {
#pragma unroll
    for (int ct = 0; ct < 4; ++ct) {
      int n = n0 + wn * 64 + ct * 16 + lm;
      size_t base = (size_t)(r0 + wm * 64 + rt * 16 + lk * 4) * 4096 + l * 1024 + n;
#pragma unroll
      for (int reg = 0; reg < 4; ++reg)
        out[base + (size_t)reg * 4096] = acc[rt][ct][reg] + bv[ct];
    }
  }
}

// ---------------- launch ---------------------------------------------------
extern "C" void kernel_launch(void* const* d_in, const int* in_sizes, int n_in,
                              void* d_out, int out_size, void* d_ws, size_t ws_size,
                              hipStream_t stream) {
  const float* x    = (const float*)d_in[0];
  const float* w1   = (const float*)d_in[1];
  const float* w2   = (const float*)d_in[2];
  const float* bias = (const float*)d_in[3];
  float* out = (float*)d_out;

  // workspace layout: Y (24 MB) | w1bf (1.5 MB) | w2bf (1.5 MB)
  unsigned short* Y    = (unsigned short*)d_ws;
  unsigned short* w1bf = (unsigned short*)((char*)d_ws + 25165824);
  unsigned short* w2bf = (unsigned short*)((char*)d_ws + 25165824 + 1572864);

  cvt_k<<<768, 256, 0, stream>>>(w1, w1bf, 786432);
  cvt_k<<<768, 256, 0, stream>>>(w2, w2bf, 786432);
  stage1_k<<<dim3(128, 4), 256, 0, stream>>>(x, w1bf, Y);
  stage2_k<<<dim3(8, 128, 4), 256, 0, stream>>>(Y, w2bf, bias, out);
}

// Round 2
// 545.107 us; speedup vs baseline: 1.0313x; 1.0313x over previous
//
#include <hip/hip_runtime.h>
#include <cstdint>
#include <cstddef>

typedef __attribute__((ext_vector_type(8))) short short8;
typedef __attribute__((ext_vector_type(4))) float f32x4;
typedef __attribute__((ext_vector_type(4))) short short4v;

__device__ __forceinline__ unsigned short f2bf(float f) {
  unsigned u = __builtin_bit_cast(unsigned, f);
  u += 0x7fffu + ((u >> 16) & 1u);   // round-to-nearest-even
  return (unsigned short)(u >> 16);
}

// ---------------- kernel 0: fp32 -> bf16 weight conversion ----------------
__global__ __launch_bounds__(256) void cvt_k(const float* __restrict__ src,
                                             unsigned short* __restrict__ dst, int n) {
  int i = (blockIdx.x * 256 + threadIdx.x) * 4;
  if (i + 3 < n) {
    float4 v = *(const float4*)(src + i);
    short4v o;
    o.x = (short)f2bf(v.x); o.y = (short)f2bf(v.y);
    o.z = (short)f2bf(v.z); o.w = (short)f2bf(v.w);
    *(short4v*)(dst + i) = o;
  }
}

// ---------------- kernel 1: stage-1 GEMM + block-transpose write ----------
// Per k-block (kb=0..3): C1[b, q] = sum_p x[b, kb*1024+p] * w1[kb, q, p]
// Written transposed: Y[b*768 + (q/48)*192 + kb*48 + (q%48)]  (bf16)
// Tile: 64 rows x 192 cols (full N), BK=64, 256 threads (2x2 wave grid).
// grid (256,4) = 1024 blocks = 4/CU; LDS 36 KB -> 4 blocks/CU.
#define S1_LDA 72   // 64 + 8 pad: 144 B row stride (16B-aligned, bank-rotating)
__global__ __launch_bounds__(256, 4) void stage1_k(
    const float* __restrict__ x, const unsigned short* __restrict__ w1bf,
    unsigned short* __restrict__ Y) {
  __shared__ __attribute__((aligned(16))) unsigned short As[64 * S1_LDA];   //  9216 B
  __shared__ __attribute__((aligned(16))) unsigned short Bs[192 * S1_LDA];  // 27648 B
  const int t  = threadIdx.x;
  const int r0 = blockIdx.x * 64;
  const int kb = blockIdx.y;

  const int lane = t & 63;
  const int w  = t >> 6;
  const int wm = w & 1, wn = w >> 1;
  const int lm = lane & 15;   // m (A) / n (B) / col (C)
  const int lk = lane >> 4;   // k-group 0..3

  f32x4 acc[2][6];
#pragma unroll
  for (int i = 0; i < 2; ++i)
#pragma unroll
    for (int j = 0; j < 6; ++j) acc[i][j] = (f32x4)0.0f;

  const float* xbase = x + (size_t)r0 * 4096 + kb * 1024;

  for (int kt = 0; kt < 16; ++kt) {
    const float* xk = xbase + kt * 64;
    // ---- stage A: 64 rows x 64 cols fp32, coalesced 32 B/lane ----
    // u = t + 256*j; row = u>>3 (8 x 8-float chunks per row), c8 = u&7.
    // 8 consecutive lanes cover one contiguous 256 B row segment.
#pragma unroll
    for (int j = 0; j < 2; ++j) {
      int u = t + 256 * j;
      int row = u >> 3, c8 = u & 7;
      const float* p = xk + (size_t)row * 4096 + c8 * 8;
      float4 a0 = *(const float4*)p;
      float4 a1 = *(const float4*)(p + 4);
      short8 o;
      o[0] = (short)f2bf(a0.x); o[1] = (short)f2bf(a0.y);
      o[2] = (short)f2bf(a0.z); o[3] = (short)f2bf(a0.w);
      o[4] = (short)f2bf(a1.x); o[5] = (short)f2bf(a1.y);
      o[6] = (short)f2bf(a1.z); o[7] = (short)f2bf(a1.w);
      *(short8*)&As[row * S1_LDA + c8 * 8] = o;
    }
    // ---- stage B: 192x64 bf16 tile of w1bf (L2-resident, 1.5 MB total) ----
#pragma unroll
    for (int i = 0; i < 6; ++i) {
      int c = t + 256 * i;          // 0..1535 chunk id (16 B each)
      int br = c >> 3, bs = c & 7;
      *(uint4*)&Bs[br * S1_LDA + bs * 8] =
          *(const uint4*)(w1bf + (size_t)(kb * 192 + br) * 1024 + kt * 64 + bs * 8);
    }
    __syncthreads();
    // ---- MFMA: 2 k-steps of 32 ----
#pragma unroll
    for (int ks = 0; ks < 2; ++ks) {
      const int ko = ks * 32 + lk * 8;
      short8 a[2], b[6];
#pragma unroll
      for (int rt = 0; rt < 2; ++rt)
        a[rt] = *(const short8*)&As[(wm * 32 + rt * 16 + lm) * S1_LDA + ko];
#pragma unroll
      for (int ct = 0; ct < 6; ++ct)
        b[ct] = *(const short8*)&Bs[(wn * 96 + ct * 16 + lm) * S1_LDA + ko];
#pragma unroll
      for (int rt = 0; rt < 2; ++rt)
#pragma unroll
        for (int ct = 0; ct < 6; ++ct)
          acc[rt][ct] = __builtin_amdgcn_mfma_f32_16x16x32_bf16(a[rt], b[ct], acc[rt][ct], 0, 0, 0);
    }
    __syncthreads();
  }

  // ---- epilogue: transposed bf16 write to Y ----
#pragma unroll
  for (int rt = 0; rt < 2; ++rt) {
#pragma unroll
    for (int ct = 0; ct < 6; ++ct) {
      int q  = wn * 96 + ct * 16 + lm;          // 0..191
      int li = q / 48, j = q - li * 48;
      size_t base = (size_t)(r0 + wm * 32 + rt * 16 + lk * 4) * 768 + li * 192 + kb * 48 + j;
#pragma unroll
      for (int reg = 0; reg < 4; ++reg)
        Y[base + (size_t)reg * 768] = f2bf(acc[rt][ct][reg]);
    }
  }
}

// ---------------- kernel 2: stage-2 GEMM + bias ---------------------------
// Per l (0..3): out[b, l*1024+s] = sum_r Y[b, l, r] * w2[l, s, r] + bias
// Tile: 128 rows x 128 cols, BK=96 (2 iters), 256 threads (2x2 wave grid).
// Epilogue: per-wave LDS transpose -> coalesced float4 stores.
#define S2_LDA 104  // 96 + 8 pad: 208 B row stride
__global__ __launch_bounds__(256) void stage2_k(
    const unsigned short* __restrict__ Y, const unsigned short* __restrict__ w2bf,
    const float* __restrict__ bias, float* __restrict__ out) {
  __shared__ __attribute__((aligned(16))) unsigned short As[128 * S2_LDA];  // 26624 B
  __shared__ __attribute__((aligned(16))) unsigned short Bs[128 * S2_LDA];  // 26624 B
  const int t  = threadIdx.x;
  const int n0 = blockIdx.x * 128;
  const int r0 = blockIdx.y * 128;
  const int l  = blockIdx.z;

  const int lane = t & 63;
  const int w  = t >> 6;
  const int wm = w & 1, wn = w >> 1;
  const int lm = lane & 15;
  const int lk = lane >> 4;

  f32x4 acc[4][4];
#pragma unroll
  for (int i = 0; i < 4; ++i)
#pragma unroll
    for (int j = 0; j < 4; ++j) acc[i][j] = (f32x4)0.0f;

  for (int kt = 0; kt < 2; ++kt) {
    // stage A (Y tile 128x96 bf16) and B (w2 tile 128x96 bf16)
#pragma unroll
    for (int i = 0; i < 6; ++i) {
      int c = t + 256 * i;          // 0..1535; 12 chunks/row
      int row = c / 12, s = c - row * 12;
      *(uint4*)&As[row * S2_LDA + s * 8] =
          *(const uint4*)(Y + (size_t)(r0 + row) * 768 + l * 192 + kt * 96 + s * 8);
      *(uint4*)&Bs[row * S2_LDA + s * 8] =
          *(const uint4*)(w2bf + (size_t)(l * 1024 + n0 + row) * 192 + kt * 96 + s * 8);
    }
    __syncthreads();
#pragma unroll
    for (int ks = 0; ks < 3; ++ks) {
      const int ko = ks * 32 + lk * 8;
      short8 a[4], b[4];
#pragma unroll
      for (int rt = 0; rt < 4; ++rt)
        a[rt] = *(const short8*)&As[(wm * 64 + rt * 16 + lm) * S2_LDA + ko];
#pragma unroll
      for (int ct = 0; ct < 4; ++ct)
        b[ct] = *(const short8*)&Bs[(wn * 64 + ct * 16 + lm) * S2_LDA + ko];
#pragma unroll
      for (int rt = 0; rt < 4; ++rt)
#pragma unroll
        for (int ct = 0; ct < 4; ++ct)
          acc[rt][ct] = __builtin_amdgcn_mfma_f32_16x16x32_bf16(a[rt], b[ct], acc[rt][ct], 0, 0, 0);
    }
    __syncthreads();
  }

  // ---- epilogue: bias + per-wave LDS transpose, coalesced float4 stores ----
  // After the final barrier all LDS reads are done; each wave reuses a
  // private 16x(64 + 4 pad) float slice of As (4352 B x 4 waves <= 17.4 KB).
  float* LF = (float*)As + w * 1088;
  float bv[4];
#pragma unroll
  for (int ct = 0; ct < 4; ++ct)
    bv[ct] = bias[l * 1024 + n0 + wn * 64 + ct * 16 + lm];

#pragma unroll
  for (int rt = 0; rt < 4; ++rt) {
#pragma unroll
    for (int ct = 0; ct < 4; ++ct)
#pragma unroll
      for (int reg = 0; reg < 4; ++reg)
        LF[(lk * 4 + reg) * 68 + ct * 16 + lm] = acc[rt][ct][reg] + bv[ct];
    // wave-local: compiler inserts lgkmcnt waits; no __syncthreads needed
#pragma unroll
    for (int it = 0; it < 4; ++it) {
      int idx = it * 64 + lane;     // 256 float4 chunks in 16x64 region
      int rr = idx >> 4, cc = idx & 15;
      float4 vv = *(const float4*)&LF[rr * 68 + cc * 4];
      *(float4*)&out[(size_t)(r0 + wm * 64 + rt * 16 + rr) * 4096 + l * 1024 + n0 + wn * 64 + cc * 4] = vv;
    }
  }
}

// ---------------- launch ---------------------------------------------------
extern "C" void kernel_launch(void* const* d_in, const int* in_sizes, int n_in,
                              void* d_out, int out_size, void* d_ws, size_t ws_size,
                              hipStream_t stream) {
  const float* x    = (const float*)d_in[0];
  const float* w1   = (const float*)d_in[1];
  const float* w2   = (const float*)d_in[2];
  const float* bias = (const float*)d_in[3];
  float* out = (float*)d_out;

  // workspace layout: Y (24 MB) | w1bf (1.5 MB) | w2bf (1.5 MB)
  unsigned short* Y    = (unsigned short*)d_ws;
  unsigned short* w1bf = (unsigned short*)((char*)d_ws + 25165824);
  unsigned short* w2bf = (unsigned short*)((char*)d_ws + 25165824 + 1572864);

  cvt_k<<<768, 256, 0, stream>>>(w1, w1bf, 786432);
  cvt_k<<<768, 256, 0, stream>>>(w2, w2bf, 786432);
  stage1_k<<<dim3(256, 4), 256, 0, stream>>>(x, w1bf, Y);
  stage2_k<<<dim3(8, 128, 4), 256, 0, stream>>>(Y, w2bf, bias, out);
}